// Round 13
// baseline (51.788 us; speedup 1.0000x reference)
//
#include <hip/hip_runtime.h>

#define EMBD 768
#define HS 64
#define S_LEN 4096
#define BK 64
#define NPAR 6

typedef __attribute__((ext_vector_type(8))) short short8;
typedef __attribute__((ext_vector_type(4))) short short4_t;
typedef __attribute__((ext_vector_type(4))) float f32x4;
typedef unsigned short ushort_t;
typedef unsigned int uint_t;

static __device__ __forceinline__ ushort_t f2bf(float f) {
    union { float f; unsigned u; } x; x.f = f;
    unsigned r = x.u + 0x7fffu + ((x.u >> 16) & 1u);   // RNE
    return (ushort_t)(r >> 16);
}

static __device__ __forceinline__ float bf2f(ushort_t u) {
    union { float f; uint_t u; } x; x.u = ((uint_t)u) << 16; return x.f;
}

static __device__ __forceinline__ uint_t cvt_pk_bf16(float lo, float hi) {
    uint_t r;
    asm volatile("v_cvt_pk_bf16_f32 %0, %1, %2" : "=v"(r) : "v"(lo), "v"(hi));
    return r;
}

static __device__ __forceinline__ short8 pack_bf8(float4 a, float4 b) {
    union { short8 s; uint_t u[4]; } r;
    r.u[0] = cvt_pk_bf16(a.x, a.y); r.u[1] = cvt_pk_bf16(a.z, a.w);
    r.u[2] = cvt_pk_bf16(b.x, b.y); r.u[3] = cvt_pk_bf16(b.z, b.w);
    return r.s;
}

static __device__ __forceinline__ void gl_lds16(const void* g, void* l) {
    __builtin_amdgcn_global_load_lds(
        (const __attribute__((address_space(1))) unsigned int*)g,
        (__attribute__((address_space(3))) unsigned int*)l, 16, 0, 0);
}

// ---------------- W prep: Wt[192][768] bf16, Wt[c][k] = W_sel[k][c%64] ----------------
// 144 blocks = 3 W x 48 chunks of 16 k-rows.
__global__ __launch_bounds__(256) void wprep_kernel(
    const float* __restrict__ Wq, const float* __restrict__ Wk, const float* __restrict__ Wv,
    ushort_t* __restrict__ Wt)
{
    __shared__ float ws[64][17];
    const int blk  = blockIdx.x;
    const int widx = blk / 48, kb = blk % 48;
    const float* W = (widx == 0) ? Wq : (widx == 1) ? Wk : Wv;
    const int k0 = kb * 16;
    const int t  = threadIdx.x;
    const int r  = t >> 4, c0 = (t & 15) * 4;
    {
        float4 v = *(const float4*)(W + (size_t)(k0 + r) * HS + c0);
        ws[c0 + 0][r] = v.x; ws[c0 + 1][r] = v.y;
        ws[c0 + 2][r] = v.z; ws[c0 + 3][r] = v.w;
    }
    __syncthreads();
    const int c = t >> 2, kc = (t & 3) * 4;
    union { short4_t s; uint_t u[2]; } p;
    p.u[0] = cvt_pk_bf16(ws[c][kc + 0], ws[c][kc + 1]);
    p.u[1] = cvt_pk_bf16(ws[c][kc + 2], ws[c][kc + 3]);
    *(short4_t*)(Wt + (size_t)(widx * 64 + c) * EMBD + k0 + kc) = p.s;
}

// ---------------- QKV via MFMA: 32-row x BK=64, gl_lds dbuf, 2 blocks/CU ---------------
__global__ __launch_bounds__(512) void qkv_kernel(
    const float* __restrict__ x, const ushort_t* __restrict__ Wt,
    ushort_t* __restrict__ Qg, ushort_t* __restrict__ Kg, ushort_t* __restrict__ Vtg)
{
    __shared__ char xA[2][8192];               // fp32 A tile [32 rows][64 k]
    __shared__ char Wl[2][24576];              // bf16 W tile [192 c][64 k]
    __shared__ float Vs[32][65];
    const int t    = threadIdx.x;
    const int w    = t >> 6;
    const int lane = t & 63;
    const int l15  = lane & 15;
    const int l4   = lane >> 4;
    const int mg   = w >> 2;                   // 0..1 (16 rows each)
    const int cg   = w & 3;                    // 0..3 (48 cols each)
    const int row0 = blockIdx.x * 32;

    const int arow_s = t >> 4, ag = t & 15;
    const float* asrc = x + (size_t)(row0 + arow_s) * EMBD + ((ag ^ (arow_s & 15)) << 2);
    const int wcs = t >> 3, wgs = t & 7;
    const ushort_t* wsrc0 = Wt + (size_t)(wcs      ) * EMBD + ((wgs ^ (wcs & 7)) << 3);
    const ushort_t* wsrc1 = Wt + (size_t)(wcs +  64) * EMBD + ((wgs ^ (wcs & 7)) << 3);
    const ushort_t* wsrc2 = Wt + (size_t)(wcs + 128) * EMBD + ((wgs ^ (wcs & 7)) << 3);

    auto stage = [&](int kt, int buf) {
        const int xo = kt * 64;
        gl_lds16(asrc + xo,  xA[buf] + w * 1024);
        gl_lds16(wsrc0 + xo, Wl[buf] + w * 1024);
        gl_lds16(wsrc1 + xo, Wl[buf] + 8192 + w * 1024);
        gl_lds16(wsrc2 + xo, Wl[buf] + 16384 + w * 1024);
    };

    const int ar = mg * 16 + l15;
    const int wc0 = cg * 48 + l15;
    const int wc1 = wc0 + 16, wc2 = wc0 + 32;

    f32x4 acc[3];
#pragma unroll
    for (int j = 0; j < 3; ++j) acc[j] = (f32x4){0.f, 0.f, 0.f, 0.f};

    stage(0, 0);
    __syncthreads();

#pragma unroll
    for (int kt = 0; kt < 12; ++kt) {
        const int cur = kt & 1;
        if (kt < 11) stage(kt + 1, cur ^ 1);
        const char* Ab = xA[cur];
        const char* Wb = Wl[cur];
#pragma unroll
        for (int ks = 0; ks < 2; ++ks) {
            const int gf = ks * 8 + 2 * l4;
            float4 a0 = *(const float4*)(Ab + ar * 256 + (((gf    ) ^ l15) << 4));
            float4 a1 = *(const float4*)(Ab + ar * 256 + (((gf + 1) ^ l15) << 4));
            short8 af = pack_bf8(a0, a1);
            const int gw = ks * 4 + l4;
            short8 wf0 = *(const short8*)(Wb + wc0 * 128 + ((gw ^ (wc0 & 7)) << 4));
            short8 wf1 = *(const short8*)(Wb + wc1 * 128 + ((gw ^ (wc1 & 7)) << 4));
            short8 wf2 = *(const short8*)(Wb + wc2 * 128 + ((gw ^ (wc2 & 7)) << 4));
            acc[0] = __builtin_amdgcn_mfma_f32_16x16x32_bf16(af, wf0, acc[0], 0, 0, 0);
            acc[1] = __builtin_amdgcn_mfma_f32_16x16x32_bf16(af, wf1, acc[1], 0, 0, 0);
            acc[2] = __builtin_amdgcn_mfma_f32_16x16x32_bf16(af, wf2, acc[2], 0, 0, 0);
        }
        if (kt < 11) __syncthreads();
    }

    const int lrow = mg * 16 + l4 * 4;
    const size_t grow = (size_t)row0 + lrow;
#pragma unroll
    for (int ct = 0; ct < 3; ++ct) {
        const int cbase = cg * 48 + ct * 16;
        const int sel   = cbase >> 6;
        const int cloc  = (cbase & 63) + l15;
#pragma unroll
        for (int r = 0; r < 4; ++r) {
            const float v = acc[ct][r];
            if (sel == 0)      Qg[(grow + r) * HS + cloc] = f2bf(v * 0.125f);
            else if (sel == 1) Kg[(grow + r) * HS + cloc] = f2bf(v);
            else               Vs[lrow + r][cloc] = v;
        }
    }
    __syncthreads();
    {
        const int vcol = t >> 3, vr0 = (t & 7) * 4;
        const int bb = row0 >> 12, s0 = row0 & 4095;
        union { short4_t s; uint_t u[2]; } vp;
        vp.u[0] = cvt_pk_bf16(Vs[vr0][vcol],     Vs[vr0 + 1][vcol]);
        vp.u[1] = cvt_pk_bf16(Vs[vr0 + 2][vcol], Vs[vr0 + 3][vcol]);
        *(short4_t*)(Vtg + ((size_t)bb * HS + vcol) * S_LEN + s0 + vr0) = vp.s;
    }
}

// ---------------- Flash attention: counted-vmcnt pipeline, 6-way key parity -----------
// 768 blocks: (b, pair jp, parity v). Phase loop over ranges jp, 63-jp. Per tile:
// s_barrier ; stage(next) ; vmcnt(4) ; s_barrier ; compute — prefetch survives barriers.
__global__ __launch_bounds__(256) void attn_kernel(
    const ushort_t* __restrict__ Qg, const ushort_t* __restrict__ Kg,
    const ushort_t* __restrict__ Vtg,
    ushort_t* __restrict__ pacc, float* __restrict__ pm, float* __restrict__ pl)
{
    __shared__ char smem[40960];   // K dbuf 16K | V dbuf 16K | P 4x2K
    const int t    = threadIdx.x;
    const int w    = t >> 6;
    const int lane = t & 63;
    const int l15  = lane & 15;
    const int l4   = lane >> 4;

    const int g  = blockIdx.x;
    const int b  = g & 3;                      // batch in low bits -> XCD spread
    const int rr = g >> 2;                     // 0..191
    const int jp = rr & 31;                    // pair index 0..31
    const int v  = rr >> 5;                    // key parity 0..5

    const ushort_t* Kb_ = Kg  + (size_t)b * S_LEN * HS;
    const ushort_t* Vb_ = Vtg + (size_t)b * HS * S_LEN;
    const ushort_t* Qb_ = Qg  + (size_t)b * S_LEN * HS;

    char* myP = smem + 32768 + w * 2048;       // P[16 q][64 k] bf16
    const int psw = (l15 & 7) << 4;

    auto stage = [&](int k0, int db) {
#pragma unroll
        for (int i = 0; i < 2; ++i) {
            const int row = w * 16 + i * 8 + (lane >> 3);
            const int c   = lane & 7;
            gl_lds16(Kb_ + (size_t)(k0 + row) * HS + ((c ^ (row & 7)) * 8),
                     smem + db * 8192 + w * 2048 + i * 1024);
            gl_lds16(Vb_ + (size_t)row * S_LEN + k0 + ((c ^ (row & 7)) * 8),
                     smem + 16384 + db * 8192 + w * 2048 + i * 1024);
        }
    };

#pragma unroll 1
    for (int ph = 0; ph < 2; ++ph) {
        const int r    = ph ? (63 - jp) : jp;
        const int pidx = (b * 64 + r) * NPAR + v;
        const int nt   = r + 1;
        const int q    = r * BK + w * 16 + l15;
        const ushort_t* qrow = Qb_ + (size_t)q * HS;
        short8 qf0 = *(const short8*)(qrow + l4 * 8);
        short8 qf1 = *(const short8*)(qrow + 32 + l4 * 8);
        f32x4 acc[4];
#pragma unroll
        for (int j = 0; j < 4; ++j) acc[j] = (f32x4){0.f,0.f,0.f,0.f};
        float mm = -3e38f, ls = 0.f;

        __syncthreads();                       // prior-phase users of smem done
        if (v < nt) stage(v * BK, 0);
        int db = 0;
#pragma unroll 1
        for (int tt = v; tt < nt; tt += NPAR, db ^= 1) {
            __builtin_amdgcn_s_barrier();      // #1: all reads of buf db^1 retired
            if (tt + NPAR < nt) {
                stage((tt + NPAR) * BK, db ^ 1);
                asm volatile("s_waitcnt vmcnt(4)" ::: "memory");   // stage(tt) done
            } else {
                asm volatile("s_waitcnt vmcnt(0)" ::: "memory");
            }
            __builtin_amdgcn_s_barrier();      // #2: every wave's stage(tt) landed
            __builtin_amdgcn_sched_barrier(0);
            const char* Kt  = smem + db * 8192;
            const char* Vt2 = smem + 16384 + db * 8192;

            f32x4 sT[4];
#pragma unroll
            for (int st = 0; st < 4; ++st) {
                const int krow = st * 16 + l15;
                const char* krb = Kt + krow * 128;
                const int sw = krow & 7;
                short8 kc0 = *(const short8*)(krb + ((l4 ^ sw) << 4));
                short8 kc1 = *(const short8*)(krb + (((4 + l4) ^ sw) << 4));
                f32x4 z = (f32x4){0.f,0.f,0.f,0.f};
                z = __builtin_amdgcn_mfma_f32_16x16x32_bf16(kc0, qf0, z, 0, 0, 0);
                z = __builtin_amdgcn_mfma_f32_16x16x32_bf16(kc1, qf1, z, 0, 0, 0);
                sT[st] = z;
            }
            if (tt == r) {                     // diagonal tile: causal mask
#pragma unroll
                for (int st = 0; st < 4; ++st)
#pragma unroll
                    for (int rr2 = 0; rr2 < 4; ++rr2)
                        if (tt * BK + st * 16 + l4 * 4 + rr2 > q) sT[st][rr2] = -3e38f;
            }
            float a0 = fmaxf(fmaxf(sT[0][0], sT[0][1]), fmaxf(sT[0][2], sT[0][3]));
            float a1 = fmaxf(fmaxf(sT[1][0], sT[1][1]), fmaxf(sT[1][2], sT[1][3]));
            float a2 = fmaxf(fmaxf(sT[2][0], sT[2][1]), fmaxf(sT[2][2], sT[2][3]));
            float a3 = fmaxf(fmaxf(sT[3][0], sT[3][1]), fmaxf(sT[3][2], sT[3][3]));
            float mt = fmaxf(fmaxf(a0, a1), fmaxf(a2, a3));
            if (__any(mt > mm + 8.f)) {        // rare: full max + rescale
                mt = fmaxf(mt, __shfl_xor(mt, 16));
                mt = fmaxf(mt, __shfl_xor(mt, 32));
                float mn = fmaxf(mm, mt);
                float corr = __expf(mm - mn);
                ls *= corr;
#pragma unroll
                for (int ds = 0; ds < 4; ++ds)
#pragma unroll
                    for (int rr2 = 0; rr2 < 4; ++rr2) acc[ds][rr2] *= corr;
                mm = mn;
            }
            char* pr = myP + l15 * 128;
            float la = 0.f;
#pragma unroll
            for (int st = 0; st < 4; ++st) {
                float p0 = __expf(sT[st][0] - mm);
                float p1 = __expf(sT[st][1] - mm);
                float p2 = __expf(sT[st][2] - mm);
                float p3 = __expf(sT[st][3] - mm);
                la += (p0 + p1) + (p2 + p3);
                uint2 pk; pk.x = cvt_pk_bf16(p0, p1); pk.y = cvt_pk_bf16(p2, p3);
                *(uint2*)(pr + ((st * 32 + l4 * 8) ^ psw)) = pk;
            }
            ls += la;
            short8 pb0 = *(const short8*)(pr + ((l4 * 16) ^ psw));
            short8 pb1 = *(const short8*)(pr + ((64 + l4 * 16) ^ psw));
#pragma unroll
            for (int ds = 0; ds < 4; ++ds) {
                const int vrow = ds * 16 + l15;
                const char* vrb = Vt2 + vrow * 128;
                const int sw2 = vrow & 7;
                short8 v0 = *(const short8*)(vrb + ((l4 ^ sw2) << 4));
                short8 v1 = *(const short8*)(vrb + (((4 + l4) ^ sw2) << 4));
                acc[ds] = __builtin_amdgcn_mfma_f32_16x16x32_bf16(v0, pb0, acc[ds], 0, 0, 0);
                acc[ds] = __builtin_amdgcn_mfma_f32_16x16x32_bf16(v1, pb1, acc[ds], 0, 0, 0);
            }
        }

        ls += __shfl_xor(ls, 16);
        ls += __shfl_xor(ls, 32);
        ushort_t* pa = pacc + ((size_t)pidx * 64 + w * 16 + l15) * 64 + l4 * 4;
#pragma unroll
        for (int ds = 0; ds < 4; ++ds) {
            uint2 pk;
            pk.x = cvt_pk_bf16(acc[ds][0], acc[ds][1]);
            pk.y = cvt_pk_bf16(acc[ds][2], acc[ds][3]);
            *(uint2*)(pa + ds * 16) = pk;
        }
        if (l4 == 0) {
            pm[pidx * 64 + w * 16 + l15] = mm;
            pl[pidx * 64 + w * 16 + l15] = ls;
        }
    }
}

// ---------------- Stage 2: combine the 6 parity partials per 64-row range -------------
__global__ __launch_bounds__(256) void combine_kernel(
    const ushort_t* __restrict__ pacc, const float* __restrict__ pm, const float* __restrict__ pl,
    float* __restrict__ out)
{
    const int g   = blockIdx.x;        // b*64 + r
    const int t   = threadIdx.x;
    const int row = t >> 2;            // 0..63
    const int d0  = (t & 3) * 16;
    float mv[NPAR], lv[NPAR];
#pragma unroll
    for (int p = 0; p < NPAR; ++p) {
        mv[p] = pm[(g * NPAR + p) * 64 + row];
        lv[p] = pl[(g * NPAR + p) * 64 + row];
    }
    float ms = mv[0];
#pragma unroll
    for (int p = 1; p < NPAR; ++p) ms = fmaxf(ms, mv[p]);
    float e[NPAR], ll = 0.f;
#pragma unroll
    for (int p = 0; p < NPAR; ++p) { e[p] = __expf(mv[p] - ms); ll += lv[p] * e[p]; }
    const float inv = 1.f / ll;
    float o[16];
#pragma unroll
    for (int i = 0; i < 16; ++i) o[i] = 0.f;
#pragma unroll
    for (int p = 0; p < NPAR; ++p) {
        const ushort_t* src = pacc + ((size_t)(g * NPAR + p) * 64 + row) * 64 + d0;
        short8 s0 = *(const short8*)(src);
        short8 s1 = *(const short8*)(src + 8);
#pragma unroll
        for (int i = 0; i < 8; ++i) {
            o[i]     += bf2f((ushort_t)s0[i]) * e[p];
            o[8 + i] += bf2f((ushort_t)s1[i]) * e[p];
        }
    }
    float4* op = (float4*)&out[((size_t)g * 64 + row) * 64 + d0];
#pragma unroll
    for (int i = 0; i < 4; ++i)
        op[i] = make_float4(o[i*4] * inv, o[i*4+1] * inv, o[i*4+2] * inv, o[i*4+3] * inv);
}

extern "C" void kernel_launch(void* const* d_in, const int* in_sizes, int n_in,
                              void* d_out, int out_size, void* d_ws, size_t ws_size,
                              hipStream_t stream) {
    const float* x  = (const float*)d_in[0];
    const float* Wq = (const float*)d_in[1];
    const float* Wk = (const float*)d_in[2];
    const float* Wv = (const float*)d_in[3];
    float* out = (float*)d_out;

    const int rows = in_sizes[0] / EMBD;   // B*S = 16384
    const int B    = rows / S_LEN;         // 4

    ushort_t* Qb = (ushort_t*)d_ws;
    ushort_t* Kb = Qb + (size_t)rows * HS;
    ushort_t* Vt = Kb + (size_t)rows * HS;
    ushort_t* Wt = Vt + (size_t)rows * HS;
    ushort_t* pacc = Wt + 192 * EMBD;                        // bf16 [B*64*6][64][64]
    float* pm = (float*)(pacc + (size_t)B * 64 * NPAR * 64 * 64);
    float* pl = pm + (size_t)B * 64 * NPAR * 64;

    hipLaunchKernelGGL(wprep_kernel, dim3(144), dim3(256), 0, stream, Wq, Wk, Wv, Wt);
    hipLaunchKernelGGL(qkv_kernel, dim3(rows / 32), dim3(512), 0, stream,
                       x, Wt, Qb, Kb, Vt);
    hipLaunchKernelGGL(attn_kernel, dim3(B * 32 * NPAR), dim3(256), 0, stream,
                       Qb, Kb, Vt, pacc, pm, pl);
    hipLaunchKernelGGL(combine_kernel, dim3(B * 64), dim3(256), 0, stream,
                       pacc, pm, pl, out);
}

// Round 14
// 51.604 us; speedup vs baseline: 1.0036x; 1.0036x over previous
//
#include <hip/hip_runtime.h>

#define EMBD 768
#define HS 64
#define S_LEN 4096
#define BK 64
#define NPAR 8

typedef __attribute__((ext_vector_type(8))) short short8;
typedef __attribute__((ext_vector_type(4))) short short4_t;
typedef __attribute__((ext_vector_type(4))) float f32x4;
typedef unsigned short ushort_t;
typedef unsigned int uint_t;

static __device__ __forceinline__ ushort_t f2bf(float f) {
    union { float f; unsigned u; } x; x.f = f;
    unsigned r = x.u + 0x7fffu + ((x.u >> 16) & 1u);   // RNE
    return (ushort_t)(r >> 16);
}

static __device__ __forceinline__ float bf2f(ushort_t u) {
    union { float f; uint_t u; } x; x.u = ((uint_t)u) << 16; return x.f;
}

static __device__ __forceinline__ uint_t cvt_pk_bf16(float lo, float hi) {
    uint_t r;
    asm volatile("v_cvt_pk_bf16_f32 %0, %1, %2" : "=v"(r) : "v"(lo), "v"(hi));
    return r;
}

static __device__ __forceinline__ short8 pack_bf8(float4 a, float4 b) {
    union { short8 s; uint_t u[4]; } r;
    r.u[0] = cvt_pk_bf16(a.x, a.y); r.u[1] = cvt_pk_bf16(a.z, a.w);
    r.u[2] = cvt_pk_bf16(b.x, b.y); r.u[3] = cvt_pk_bf16(b.z, b.w);
    return r.s;
}

static __device__ __forceinline__ void gl_lds16(const void* g, void* l) {
    __builtin_amdgcn_global_load_lds(
        (const __attribute__((address_space(1))) unsigned int*)g,
        (__attribute__((address_space(3))) unsigned int*)l, 16, 0, 0);
}

// ---------------- W prep: Wt[192][768] bf16, Wt[c][k] = W_sel[k][c%64] ----------------
__global__ __launch_bounds__(256) void wprep_kernel(
    const float* __restrict__ Wq, const float* __restrict__ Wk, const float* __restrict__ Wv,
    ushort_t* __restrict__ Wt)
{
    __shared__ float ws[64][17];
    const int blk  = blockIdx.x;
    const int widx = blk / 48, kb = blk % 48;
    const float* W = (widx == 0) ? Wq : (widx == 1) ? Wk : Wv;
    const int k0 = kb * 16;
    const int t  = threadIdx.x;
    const int r  = t >> 4, c0 = (t & 15) * 4;
    {
        float4 v = *(const float4*)(W + (size_t)(k0 + r) * HS + c0);
        ws[c0 + 0][r] = v.x; ws[c0 + 1][r] = v.y;
        ws[c0 + 2][r] = v.z; ws[c0 + 3][r] = v.w;
    }
    __syncthreads();
    const int c = t >> 2, kc = (t & 3) * 4;
    union { short4_t s; uint_t u[2]; } p;
    p.u[0] = cvt_pk_bf16(ws[c][kc + 0], ws[c][kc + 1]);
    p.u[1] = cvt_pk_bf16(ws[c][kc + 2], ws[c][kc + 3]);
    *(short4_t*)(Wt + (size_t)(widx * 64 + c) * EMBD + k0 + kc) = p.s;
}

// ---------------- QKV via MFMA: 32-row x BK=64, gl_lds dbuf, 2 blocks/CU ---------------
__global__ __launch_bounds__(512) void qkv_kernel(
    const float* __restrict__ x, const ushort_t* __restrict__ Wt,
    ushort_t* __restrict__ Qg, ushort_t* __restrict__ Kg, ushort_t* __restrict__ Vtg)
{
    __shared__ char xA[2][8192];               // fp32 A tile [32 rows][64 k]
    __shared__ char Wl[2][24576];              // bf16 W tile [192 c][64 k]
    __shared__ float Vs[32][65];
    const int t    = threadIdx.x;
    const int w    = t >> 6;
    const int lane = t & 63;
    const int l15  = lane & 15;
    const int l4   = lane >> 4;
    const int mg   = w >> 2;                   // 0..1 (16 rows each)
    const int cg   = w & 3;                    // 0..3 (48 cols each)
    const int row0 = blockIdx.x * 32;

    const int arow_s = t >> 4, ag = t & 15;
    const float* asrc = x + (size_t)(row0 + arow_s) * EMBD + ((ag ^ (arow_s & 15)) << 2);
    const int wcs = t >> 3, wgs = t & 7;
    const ushort_t* wsrc0 = Wt + (size_t)(wcs      ) * EMBD + ((wgs ^ (wcs & 7)) << 3);
    const ushort_t* wsrc1 = Wt + (size_t)(wcs +  64) * EMBD + ((wgs ^ (wcs & 7)) << 3);
    const ushort_t* wsrc2 = Wt + (size_t)(wcs + 128) * EMBD + ((wgs ^ (wcs & 7)) << 3);

    auto stage = [&](int kt, int buf) {
        const int xo = kt * 64;
        gl_lds16(asrc + xo,  xA[buf] + w * 1024);
        gl_lds16(wsrc0 + xo, Wl[buf] + w * 1024);
        gl_lds16(wsrc1 + xo, Wl[buf] + 8192 + w * 1024);
        gl_lds16(wsrc2 + xo, Wl[buf] + 16384 + w * 1024);
    };

    const int ar = mg * 16 + l15;
    const int wc0 = cg * 48 + l15;
    const int wc1 = wc0 + 16, wc2 = wc0 + 32;

    f32x4 acc[3];
#pragma unroll
    for (int j = 0; j < 3; ++j) acc[j] = (f32x4){0.f, 0.f, 0.f, 0.f};

    stage(0, 0);
    __syncthreads();

#pragma unroll
    for (int kt = 0; kt < 12; ++kt) {
        const int cur = kt & 1;
        if (kt < 11) stage(kt + 1, cur ^ 1);
        const char* Ab = xA[cur];
        const char* Wb = Wl[cur];
#pragma unroll
        for (int ks = 0; ks < 2; ++ks) {
            const int gf = ks * 8 + 2 * l4;
            float4 a0 = *(const float4*)(Ab + ar * 256 + (((gf    ) ^ l15) << 4));
            float4 a1 = *(const float4*)(Ab + ar * 256 + (((gf + 1) ^ l15) << 4));
            short8 af = pack_bf8(a0, a1);
            const int gw = ks * 4 + l4;
            short8 wf0 = *(const short8*)(Wb + wc0 * 128 + ((gw ^ (wc0 & 7)) << 4));
            short8 wf1 = *(const short8*)(Wb + wc1 * 128 + ((gw ^ (wc1 & 7)) << 4));
            short8 wf2 = *(const short8*)(Wb + wc2 * 128 + ((gw ^ (wc2 & 7)) << 4));
            acc[0] = __builtin_amdgcn_mfma_f32_16x16x32_bf16(af, wf0, acc[0], 0, 0, 0);
            acc[1] = __builtin_amdgcn_mfma_f32_16x16x32_bf16(af, wf1, acc[1], 0, 0, 0);
            acc[2] = __builtin_amdgcn_mfma_f32_16x16x32_bf16(af, wf2, acc[2], 0, 0, 0);
        }
        if (kt < 11) __syncthreads();
    }

    const int lrow = mg * 16 + l4 * 4;
    const size_t grow = (size_t)row0 + lrow;
#pragma unroll
    for (int ct = 0; ct < 3; ++ct) {
        const int cbase = cg * 48 + ct * 16;
        const int sel   = cbase >> 6;
        const int cloc  = (cbase & 63) + l15;
#pragma unroll
        for (int r = 0; r < 4; ++r) {
            const float v = acc[ct][r];
            if (sel == 0)      Qg[(grow + r) * HS + cloc] = f2bf(v * 0.125f);
            else if (sel == 1) Kg[(grow + r) * HS + cloc] = f2bf(v);
            else               Vs[lrow + r][cloc] = v;
        }
    }
    __syncthreads();
    {
        const int vcol = t >> 3, vr0 = (t & 7) * 4;
        const int bb = row0 >> 12, s0 = row0 & 4095;
        union { short4_t s; uint_t u[2]; } vp;
        vp.u[0] = cvt_pk_bf16(Vs[vr0][vcol],     Vs[vr0 + 1][vcol]);
        vp.u[1] = cvt_pk_bf16(Vs[vr0 + 2][vcol], Vs[vr0 + 3][vcol]);
        *(short4_t*)(Vtg + ((size_t)bb * HS + vcol) * S_LEN + s0 + vr0) = vp.s;
    }
}

// ---------------- Flash attention: 8-way key parity, 4 blocks/CU, counted vmcnt -------
// 1024 blocks: (b, pair jp, parity v in 0..7). Phase loop over ranges jp, 63-jp.
// Per tile: s_barrier ; stage(next) ; vmcnt(4) ; s_barrier ; compute.
__global__ __launch_bounds__(256, 4) void attn_kernel(
    const ushort_t* __restrict__ Qg, const ushort_t* __restrict__ Kg,
    const ushort_t* __restrict__ Vtg,
    ushort_t* __restrict__ pacc, float* __restrict__ pm, float* __restrict__ pl)
{
    __shared__ char smem[40960];   // K dbuf 16K | V dbuf 16K | P 4x2K
    const int t    = threadIdx.x;
    const int w    = t >> 6;
    const int lane = t & 63;
    const int l15  = lane & 15;
    const int l4   = lane >> 4;

    const int g  = blockIdx.x;
    const int b  = g & 3;                      // batch in low bits -> XCD spread
    const int rr = g >> 2;                     // 0..255
    const int jp = rr & 31;                    // pair index 0..31
    const int v  = rr >> 5;                    // key parity 0..7

    const ushort_t* Kb_ = Kg  + (size_t)b * S_LEN * HS;
    const ushort_t* Vb_ = Vtg + (size_t)b * HS * S_LEN;
    const ushort_t* Qb_ = Qg  + (size_t)b * S_LEN * HS;

    char* myP = smem + 32768 + w * 2048;       // P[16 q][64 k] bf16
    const int psw = (l15 & 7) << 4;

    auto stage = [&](int k0, int db) {
#pragma unroll
        for (int i = 0; i < 2; ++i) {
            const int row = w * 16 + i * 8 + (lane >> 3);
            const int c   = lane & 7;
            gl_lds16(Kb_ + (size_t)(k0 + row) * HS + ((c ^ (row & 7)) * 8),
                     smem + db * 8192 + w * 2048 + i * 1024);
            gl_lds16(Vb_ + (size_t)row * S_LEN + k0 + ((c ^ (row & 7)) * 8),
                     smem + 16384 + db * 8192 + w * 2048 + i * 1024);
        }
    };

#pragma unroll 1
    for (int ph = 0; ph < 2; ++ph) {
        const int r    = ph ? (63 - jp) : jp;
        const int pidx = (b * 64 + r) * NPAR + v;
        const int nt   = r + 1;
        const int q    = r * BK + w * 16 + l15;
        const ushort_t* qrow = Qb_ + (size_t)q * HS;
        short8 qf0 = *(const short8*)(qrow + l4 * 8);
        short8 qf1 = *(const short8*)(qrow + 32 + l4 * 8);
        f32x4 acc[4];
#pragma unroll
        for (int j = 0; j < 4; ++j) acc[j] = (f32x4){0.f,0.f,0.f,0.f};
        float mm = -3e38f, ls = 0.f;

        __syncthreads();                       // prior-phase users of smem done
        if (v < nt) stage(v * BK, 0);
        int db = 0;
#pragma unroll 1
        for (int tt = v; tt < nt; tt += NPAR, db ^= 1) {
            __builtin_amdgcn_s_barrier();      // #1: all reads of buf db^1 retired
            if (tt + NPAR < nt) {
                stage((tt + NPAR) * BK, db ^ 1);
                asm volatile("s_waitcnt vmcnt(4)" ::: "memory");   // stage(tt) done
            } else {
                asm volatile("s_waitcnt vmcnt(0)" ::: "memory");
            }
            __builtin_amdgcn_s_barrier();      // #2: every wave's stage(tt) landed
            const char* Kt  = smem + db * 8192;
            const char* Vt2 = smem + 16384 + db * 8192;

            f32x4 sT[4];
#pragma unroll
            for (int st = 0; st < 4; ++st) {
                const int krow = st * 16 + l15;
                const char* krb = Kt + krow * 128;
                const int sw = krow & 7;
                short8 kc0 = *(const short8*)(krb + ((l4 ^ sw) << 4));
                short8 kc1 = *(const short8*)(krb + (((4 + l4) ^ sw) << 4));
                f32x4 z = (f32x4){0.f,0.f,0.f,0.f};
                z = __builtin_amdgcn_mfma_f32_16x16x32_bf16(kc0, qf0, z, 0, 0, 0);
                z = __builtin_amdgcn_mfma_f32_16x16x32_bf16(kc1, qf1, z, 0, 0, 0);
                sT[st] = z;
            }
            if (tt == r) {                     // diagonal tile: causal mask
#pragma unroll
                for (int st = 0; st < 4; ++st)
#pragma unroll
                    for (int rr2 = 0; rr2 < 4; ++rr2)
                        if (tt * BK + st * 16 + l4 * 4 + rr2 > q) sT[st][rr2] = -3e38f;
            }
            float a0 = fmaxf(fmaxf(sT[0][0], sT[0][1]), fmaxf(sT[0][2], sT[0][3]));
            float a1 = fmaxf(fmaxf(sT[1][0], sT[1][1]), fmaxf(sT[1][2], sT[1][3]));
            float a2 = fmaxf(fmaxf(sT[2][0], sT[2][1]), fmaxf(sT[2][2], sT[2][3]));
            float a3 = fmaxf(fmaxf(sT[3][0], sT[3][1]), fmaxf(sT[3][2], sT[3][3]));
            float mt = fmaxf(fmaxf(a0, a1), fmaxf(a2, a3));
            if (__any(mt > mm + 8.f)) {        // rare: full max + rescale
                mt = fmaxf(mt, __shfl_xor(mt, 16));
                mt = fmaxf(mt, __shfl_xor(mt, 32));
                float mn = fmaxf(mm, mt);
                float corr = __expf(mm - mn);
                ls *= corr;
#pragma unroll
                for (int ds = 0; ds < 4; ++ds)
#pragma unroll
                    for (int rr2 = 0; rr2 < 4; ++rr2) acc[ds][rr2] *= corr;
                mm = mn;
            }
            char* pr = myP + l15 * 128;
            float la = 0.f;
#pragma unroll
            for (int st = 0; st < 4; ++st) {
                float p0 = __expf(sT[st][0] - mm);
                float p1 = __expf(sT[st][1] - mm);
                float p2 = __expf(sT[st][2] - mm);
                float p3 = __expf(sT[st][3] - mm);
                la += (p0 + p1) + (p2 + p3);
                uint2 pk; pk.x = cvt_pk_bf16(p0, p1); pk.y = cvt_pk_bf16(p2, p3);
                *(uint2*)(pr + ((st * 32 + l4 * 8) ^ psw)) = pk;
            }
            ls += la;
            short8 pb0 = *(const short8*)(pr + ((l4 * 16) ^ psw));
            short8 pb1 = *(const short8*)(pr + ((64 + l4 * 16) ^ psw));
#pragma unroll
            for (int ds = 0; ds < 4; ++ds) {
                const int vrow = ds * 16 + l15;
                const char* vrb = Vt2 + vrow * 128;
                const int sw2 = vrow & 7;
                short8 v0 = *(const short8*)(vrb + ((l4 ^ sw2) << 4));
                short8 v1 = *(const short8*)(vrb + (((4 + l4) ^ sw2) << 4));
                acc[ds] = __builtin_amdgcn_mfma_f32_16x16x32_bf16(v0, pb0, acc[ds], 0, 0, 0);
                acc[ds] = __builtin_amdgcn_mfma_f32_16x16x32_bf16(v1, pb1, acc[ds], 0, 0, 0);
            }
        }

        ls += __shfl_xor(ls, 16);
        ls += __shfl_xor(ls, 32);
        ushort_t* pa = pacc + ((size_t)pidx * 64 + w * 16 + l15) * 64 + l4 * 4;
#pragma unroll
        for (int ds = 0; ds < 4; ++ds) {
            uint2 pk;
            pk.x = cvt_pk_bf16(acc[ds][0], acc[ds][1]);
            pk.y = cvt_pk_bf16(acc[ds][2], acc[ds][3]);
            *(uint2*)(pa + ds * 16) = pk;
        }
        if (l4 == 0) {
            pm[pidx * 64 + w * 16 + l15] = mm;
            pl[pidx * 64 + w * 16 + l15] = ls;
        }
    }
}

// ---------------- Stage 2: combine the 8 parity partials per 64-row range -------------
__global__ __launch_bounds__(256) void combine_kernel(
    const ushort_t* __restrict__ pacc, const float* __restrict__ pm, const float* __restrict__ pl,
    float* __restrict__ out)
{
    const int g   = blockIdx.x;        // b*64 + r
    const int t   = threadIdx.x;
    const int row = t >> 2;            // 0..63
    const int d0  = (t & 3) * 16;
    float mv[NPAR], lv[NPAR];
#pragma unroll
    for (int p = 0; p < NPAR; ++p) {
        mv[p] = pm[(g * NPAR + p) * 64 + row];
        lv[p] = pl[(g * NPAR + p) * 64 + row];
    }
    float ms = mv[0];
#pragma unroll
    for (int p = 1; p < NPAR; ++p) ms = fmaxf(ms, mv[p]);
    float e[NPAR], ll = 0.f;
#pragma unroll
    for (int p = 0; p < NPAR; ++p) { e[p] = __expf(mv[p] - ms); ll += lv[p] * e[p]; }
    const float inv = 1.f / ll;
    float o[16];
#pragma unroll
    for (int i = 0; i < 16; ++i) o[i] = 0.f;
#pragma unroll
    for (int p = 0; p < NPAR; ++p) {
        const ushort_t* src = pacc + ((size_t)(g * NPAR + p) * 64 + row) * 64 + d0;
        short8 s0 = *(const short8*)(src);
        short8 s1 = *(const short8*)(src + 8);
#pragma unroll
        for (int i = 0; i < 8; ++i) {
            o[i]     += bf2f((ushort_t)s0[i]) * e[p];
            o[8 + i] += bf2f((ushort_t)s1[i]) * e[p];
        }
    }
    float4* op = (float4*)&out[((size_t)g * 64 + row) * 64 + d0];
#pragma unroll
    for (int i = 0; i < 4; ++i)
        op[i] = make_float4(o[i*4] * inv, o[i*4+1] * inv, o[i*4+2] * inv, o[i*4+3] * inv);
}

extern "C" void kernel_launch(void* const* d_in, const int* in_sizes, int n_in,
                              void* d_out, int out_size, void* d_ws, size_t ws_size,
                              hipStream_t stream) {
    const float* x  = (const float*)d_in[0];
    const float* Wq = (const float*)d_in[1];
    const float* Wk = (const float*)d_in[2];
    const float* Wv = (const float*)d_in[3];
    float* out = (float*)d_out;

    const int rows = in_sizes[0] / EMBD;   // B*S = 16384
    const int B    = rows / S_LEN;         // 4

    ushort_t* Qb = (ushort_t*)d_ws;
    ushort_t* Kb = Qb + (size_t)rows * HS;
    ushort_t* Vt = Kb + (size_t)rows * HS;
    ushort_t* Wt = Vt + (size_t)rows * HS;
    ushort_t* pacc = Wt + 192 * EMBD;                        // bf16 [B*64*8][64][64]
    float* pm = (float*)(pacc + (size_t)B * 64 * NPAR * 64 * 64);
    float* pl = pm + (size_t)B * 64 * NPAR * 64;

    hipLaunchKernelGGL(wprep_kernel, dim3(144), dim3(256), 0, stream, Wq, Wk, Wv, Wt);
    hipLaunchKernelGGL(qkv_kernel, dim3(rows / 32), dim3(512), 0, stream,
                       x, Wt, Qb, Kb, Vt);
    hipLaunchKernelGGL(attn_kernel, dim3(B * 32 * NPAR), dim3(256), 0, stream,
                       Qb, Kb, Vt, pacc, pm, pl);
    hipLaunchKernelGGL(combine_kernel, dim3(B * 64), dim3(256), 0, stream,
                       pacc, pm, pl, out);
}

// Round 17
// 50.797 us; speedup vs baseline: 1.0195x; 1.0159x over previous
//
#include <hip/hip_runtime.h>

#define EMBD 768
#define HS 64
#define S_LEN 4096
#define BK 64
#define NPAR 6

typedef __attribute__((ext_vector_type(8))) short short8;
typedef __attribute__((ext_vector_type(4))) short short4_t;
typedef __attribute__((ext_vector_type(4))) float f32x4;
typedef unsigned short ushort_t;
typedef unsigned int uint_t;

static __device__ __forceinline__ ushort_t f2bf(float f) {
    union { float f; unsigned u; } x; x.f = f;
    unsigned r = x.u + 0x7fffu + ((x.u >> 16) & 1u);   // RNE
    return (ushort_t)(r >> 16);
}

static __device__ __forceinline__ float bf2f(ushort_t u) {
    union { float f; uint_t u; } x; x.u = ((uint_t)u) << 16; return x.f;
}

static __device__ __forceinline__ uint_t cvt_pk_bf16(float lo, float hi) {
    uint_t r;
    asm volatile("v_cvt_pk_bf16_f32 %0, %1, %2" : "=v"(r) : "v"(lo), "v"(hi));
    return r;
}

static __device__ __forceinline__ short8 pack_bf8(float4 a, float4 b) {
    union { short8 s; uint_t u[4]; } r;
    r.u[0] = cvt_pk_bf16(a.x, a.y); r.u[1] = cvt_pk_bf16(a.z, a.w);
    r.u[2] = cvt_pk_bf16(b.x, b.y); r.u[3] = cvt_pk_bf16(b.z, b.w);
    return r.s;
}

static __device__ __forceinline__ void gl_lds16(const void* g, void* l) {
    __builtin_amdgcn_global_load_lds(
        (const __attribute__((address_space(1))) unsigned int*)g,
        (__attribute__((address_space(3))) unsigned int*)l, 16, 0, 0);
}

// ---------------- W prep: Wt[192][768] bf16, Wt[c][k] = W_sel[k][c%64] ----------------
__global__ __launch_bounds__(256) void wprep_kernel(
    const float* __restrict__ Wq, const float* __restrict__ Wk, const float* __restrict__ Wv,
    ushort_t* __restrict__ Wt)
{
    __shared__ float ws[64][65];
    const int blk  = blockIdx.x;           // 36 = 3 W x 12 k-blocks
    const int widx = blk / 12, kblk = blk % 12;
    const float* W = (widx == 0) ? Wq : (widx == 1) ? Wk : Wv;
    const int k0 = kblk * 64;
    const int t  = threadIdx.x;
    const int r  = t >> 2, c0 = (t & 3) * 16;
#pragma unroll
    for (int i = 0; i < 4; ++i) {
        float4 v = *(const float4*)(W + (size_t)(k0 + r) * HS + c0 + i * 4);
        ws[c0 + i*4 + 0][r] = v.x; ws[c0 + i*4 + 1][r] = v.y;
        ws[c0 + i*4 + 2][r] = v.z; ws[c0 + i*4 + 3][r] = v.w;
    }
    __syncthreads();
    const int c = t >> 2, kc = (t & 3) * 16;
    ushort_t* dst = Wt + (size_t)(widx * 64 + c) * EMBD + k0 + kc;
#pragma unroll
    for (int i = 0; i < 4; ++i) {
        short4_t p = {(short)f2bf(ws[c][kc + i*4 + 0]), (short)f2bf(ws[c][kc + i*4 + 1]),
                      (short)f2bf(ws[c][kc + i*4 + 2]), (short)f2bf(ws[c][kc + i*4 + 3])};
        *(short4_t*)(dst + i * 4) = p;
    }
}

// ---------------- QKV via MFMA: 32-row x BK=64, gl_lds dbuf, 2 blocks/CU ---------------
// 512 blocks x 512 thr (8 waves = 2 mg x 4 cg). LDS: A fp32 [32][64] dbuf (16KB ea,
// granule16 ^ (row&15)); W bf16 [192][64] dbuf (24KB ea, granule16 ^ (c&7)).
// 6 MFMAs per barrier.
__global__ __launch_bounds__(512) void qkv_kernel(
    const float* __restrict__ x, const ushort_t* __restrict__ Wt,
    ushort_t* __restrict__ Qg, ushort_t* __restrict__ Kg, ushort_t* __restrict__ Vtg)
{
    __shared__ char xA[2][8192];               // fp32 A tile [32 rows][64 k]
    __shared__ char Wl[2][24576];              // bf16 W tile [192 c][64 k]
    __shared__ float Vs[32][65];
    const int t    = threadIdx.x;
    const int w    = t >> 6;
    const int lane = t & 63;
    const int l15  = lane & 15;
    const int l4   = lane >> 4;
    const int mg   = w >> 2;                   // 0..1 (16 rows each)
    const int cg   = w & 3;                    // 0..3 (48 cols each)
    const int row0 = blockIdx.x * 32;

    // ---- staging maps (linear LDS dest, pre-swizzled global source)
    // A: 512 granule16/buf; thread t -> (row=t>>4, pos=t&15), content granule pos^(row&15)
    const int arow_s = t >> 4, ag = t & 15;
    const float* asrc = x + (size_t)(row0 + arow_s) * EMBD + ((ag ^ (arow_s & 15)) << 2);
    // W: 1536 granule16/buf; chunk j: idx=j*512+t -> (c=idx>>3, pos=idx&7), content pos^(c&7)
    const int wcs = t >> 3, wgs = t & 7;
    const ushort_t* wsrc0 = Wt + (size_t)(wcs      ) * EMBD + ((wgs ^ (wcs & 7)) << 3);
    const ushort_t* wsrc1 = Wt + (size_t)(wcs +  64) * EMBD + ((wgs ^ (wcs & 7)) << 3);
    const ushort_t* wsrc2 = Wt + (size_t)(wcs + 128) * EMBD + ((wgs ^ (wcs & 7)) << 3);

    auto stage = [&](int kt, int buf) {
        const int xo = kt * 64;                // elements along k
        gl_lds16(asrc + xo,  xA[buf] + w * 1024);
        gl_lds16(wsrc0 + xo, Wl[buf] + w * 1024);
        gl_lds16(wsrc1 + xo, Wl[buf] + 8192 + w * 1024);
        gl_lds16(wsrc2 + xo, Wl[buf] + 16384 + w * 1024);
    };

    // ---- read addresses
    const int ar = mg * 16 + l15;              // A row (ar&15 == l15)
    const int wc0 = cg * 48 + l15;             // W cols for ct=0,1,2
    const int wc1 = wc0 + 16, wc2 = wc0 + 32;

    f32x4 acc[3];
#pragma unroll
    for (int j = 0; j < 3; ++j) acc[j] = (f32x4){0.f, 0.f, 0.f, 0.f};

    stage(0, 0);
    __syncthreads();

#pragma unroll
    for (int kt = 0; kt < 12; ++kt) {
        const int cur = kt & 1;
        if (kt < 11) stage(kt + 1, cur ^ 1);
        const char* Ab = xA[cur];
        const char* Wb = Wl[cur];
#pragma unroll
        for (int ks = 0; ks < 2; ++ks) {
            const int gf = ks * 8 + 2 * l4;
            float4 a0 = *(const float4*)(Ab + ar * 256 + (((gf    ) ^ l15) << 4));
            float4 a1 = *(const float4*)(Ab + ar * 256 + (((gf + 1) ^ l15) << 4));
            short8 af = pack_bf8(a0, a1);
            const int gw = ks * 4 + l4;
            short8 wf0 = *(const short8*)(Wb + wc0 * 128 + ((gw ^ (wc0 & 7)) << 4));
            short8 wf1 = *(const short8*)(Wb + wc1 * 128 + ((gw ^ (wc1 & 7)) << 4));
            short8 wf2 = *(const short8*)(Wb + wc2 * 128 + ((gw ^ (wc2 & 7)) << 4));
            acc[0] = __builtin_amdgcn_mfma_f32_16x16x32_bf16(af, wf0, acc[0], 0, 0, 0);
            acc[1] = __builtin_amdgcn_mfma_f32_16x16x32_bf16(af, wf1, acc[1], 0, 0, 0);
            acc[2] = __builtin_amdgcn_mfma_f32_16x16x32_bf16(af, wf2, acc[2], 0, 0, 0);
        }
        if (kt < 11) __syncthreads();
    }

    // ---- epilogue: Q (pre-scaled 1/8) / K direct; V via Vs transpose
    const int lrow = mg * 16 + l4 * 4;
    const size_t grow = (size_t)row0 + lrow;
#pragma unroll
    for (int ct = 0; ct < 3; ++ct) {
        const int cbase = cg * 48 + ct * 16;
        const int sel   = cbase >> 6;              // 0=Q 1=K 2=V (uniform per ct)
        const int cloc  = (cbase & 63) + l15;
#pragma unroll
        for (int r = 0; r < 4; ++r) {
            const float v = acc[ct][r];
            if (sel == 0)      Qg[(grow + r) * HS + cloc] = f2bf(v * 0.125f);
            else if (sel == 1) Kg[(grow + r) * HS + cloc] = f2bf(v);
            else               Vs[lrow + r][cloc] = v;
        }
    }
    __syncthreads();
    {   // Vt write: thread t -> col t>>3, rows (t&7)*4..+3
        const int vcol = t >> 3, vr0 = (t & 7) * 4;
        const int bb = row0 >> 12, s0 = row0 & 4095;
        union { short4_t s; uint_t u[2]; } vp;
        vp.u[0] = cvt_pk_bf16(Vs[vr0][vcol],     Vs[vr0 + 1][vcol]);
        vp.u[1] = cvt_pk_bf16(Vs[vr0 + 2][vcol], Vs[vr0 + 3][vcol]);
        *(short4_t*)(Vtg + ((size_t)bb * HS + vcol) * S_LEN + s0 + vr0) = vp.s;
    }
}

// ---------------- Flash attention: 64-q-row blocks, 6-way key parity ------------------
// 768 blocks (3/CU): (b, pair jp, parity v in 0..5). Block runs ranges jp and 63-jp;
// processes key-tiles tt ≡ v (mod 6). 4 waves = 4 q-subs share each staged K/V tile.
__global__ __launch_bounds__(256) void attn_kernel(
    const ushort_t* __restrict__ Qg, const ushort_t* __restrict__ Kg,
    const ushort_t* __restrict__ Vtg,
    ushort_t* __restrict__ pacc, float* __restrict__ pm, float* __restrict__ pl)
{
    __shared__ char smem[40960];   // K dbuf 16K | V dbuf 16K | P 4x2K
    const int t    = threadIdx.x;
    const int w    = t >> 6;
    const int lane = t & 63;
    const int l15  = lane & 15;
    const int l4   = lane >> 4;

    const int g  = blockIdx.x;
    const int b  = g & 3;                      // batch in low bits -> XCD spread
    const int rr = g >> 2;                     // 0..191
    const int jp = rr & 31;                    // pair index 0..31
    const int v  = rr >> 5;                    // key parity 0..5

    const ushort_t* Kb_ = Kg  + (size_t)b * S_LEN * HS;
    const ushort_t* Vb_ = Vtg + (size_t)b * HS * S_LEN;
    const ushort_t* Qb_ = Qg  + (size_t)b * S_LEN * HS;

    char* myP = smem + 32768 + w * 2048;       // P[16 q][64 k] bf16
    const int psw = (l15 & 7) << 4;

    auto stage = [&](int k0, int db) {
#pragma unroll
        for (int i = 0; i < 2; ++i) {
            const int row = w * 16 + i * 8 + (lane >> 3);
            const int c   = lane & 7;
            gl_lds16(Kb_ + (size_t)(k0 + row) * HS + ((c ^ (row & 7)) * 8),
                     smem + db * 8192 + w * 2048 + i * 1024);
            gl_lds16(Vb_ + (size_t)row * S_LEN + k0 + ((c ^ (row & 7)) * 8),
                     smem + 16384 + db * 8192 + w * 2048 + i * 1024);
        }
    };

    auto run_phase = [&](int r, int pidx) {
        const int q0r = r * BK;
        const int nt  = r + 1;
        const int q   = q0r + w * 16 + l15;
        const ushort_t* qrow = Qb_ + (size_t)q * HS;
        short8 qf0 = *(const short8*)(qrow + l4 * 8);
        short8 qf1 = *(const short8*)(qrow + 32 + l4 * 8);
        f32x4 acc[4];
#pragma unroll
        for (int j = 0; j < 4; ++j) acc[j] = (f32x4){0.f,0.f,0.f,0.f};
        float mm = -3e38f, ls = 0.f;

        __syncthreads();                       // prior-phase readers done
        if (v < nt) stage(v * BK, 0);
        int db = 0;
        for (int tt = v; tt < nt; tt += NPAR, db ^= 1) {
            __syncthreads();                   // staged(tt) complete (vmcnt drain)
            if (tt + NPAR < nt) stage((tt + NPAR) * BK, db ^ 1);
            const char* Kt  = smem + db * 8192;
            const char* Vt2 = smem + 16384 + db * 8192;

            f32x4 sT[4];
#pragma unroll
            for (int st = 0; st < 4; ++st) {
                const int krow = st * 16 + l15;
                const char* krb = Kt + krow * 128;
                const int sw = krow & 7;
                short8 kc0 = *(const short8*)(krb + ((l4 ^ sw) << 4));
                short8 kc1 = *(const short8*)(krb + (((4 + l4) ^ sw) << 4));
                f32x4 z = (f32x4){0.f,0.f,0.f,0.f};
                z = __builtin_amdgcn_mfma_f32_16x16x32_bf16(kc0, qf0, z, 0, 0, 0);
                z = __builtin_amdgcn_mfma_f32_16x16x32_bf16(kc1, qf1, z, 0, 0, 0);
                sT[st] = z;
            }
            if (tt == r) {                     // diagonal tile: causal mask
#pragma unroll
                for (int st = 0; st < 4; ++st)
#pragma unroll
                    for (int rr2 = 0; rr2 < 4; ++rr2)
                        if (tt * BK + st * 16 + l4 * 4 + rr2 > q) sT[st][rr2] = -3e38f;
            }
            float a0 = fmaxf(fmaxf(sT[0][0], sT[0][1]), fmaxf(sT[0][2], sT[0][3]));
            float a1 = fmaxf(fmaxf(sT[1][0], sT[1][1]), fmaxf(sT[1][2], sT[1][3]));
            float a2 = fmaxf(fmaxf(sT[2][0], sT[2][1]), fmaxf(sT[2][2], sT[2][3]));
            float a3 = fmaxf(fmaxf(sT[3][0], sT[3][1]), fmaxf(sT[3][2], sT[3][3]));
            float mt = fmaxf(fmaxf(a0, a1), fmaxf(a2, a3));
            if (__any(mt > mm + 8.f)) {        // rare: full max + rescale
                mt = fmaxf(mt, __shfl_xor(mt, 16));
                mt = fmaxf(mt, __shfl_xor(mt, 32));
                float mn = fmaxf(mm, mt);
                float corr = __expf(mm - mn);
                ls *= corr;
#pragma unroll
                for (int ds = 0; ds < 4; ++ds)
#pragma unroll
                    for (int rr2 = 0; rr2 < 4; ++rr2) acc[ds][rr2] *= corr;
                mm = mn;
            }
            char* pr = myP + l15 * 128;
            float la = 0.f;
#pragma unroll
            for (int st = 0; st < 4; ++st) {
                float p0 = __expf(sT[st][0] - mm);
                float p1 = __expf(sT[st][1] - mm);
                float p2 = __expf(sT[st][2] - mm);
                float p3 = __expf(sT[st][3] - mm);
                la += (p0 + p1) + (p2 + p3);
                uint2 pk; pk.x = cvt_pk_bf16(p0, p1); pk.y = cvt_pk_bf16(p2, p3);
                *(uint2*)(pr + ((st * 32 + l4 * 8) ^ psw)) = pk;
            }
            ls += la;
            short8 pb0 = *(const short8*)(pr + ((l4 * 16) ^ psw));
            short8 pb1 = *(const short8*)(pr + ((64 + l4 * 16) ^ psw));
#pragma unroll
            for (int ds = 0; ds < 4; ++ds) {
                const int vrow = ds * 16 + l15;
                const char* vrb = Vt2 + vrow * 128;
                const int sw2 = vrow & 7;
                short8 v0 = *(const short8*)(vrb + ((l4 ^ sw2) << 4));
                short8 v1 = *(const short8*)(vrb + (((4 + l4) ^ sw2) << 4));
                acc[ds] = __builtin_amdgcn_mfma_f32_16x16x32_bf16(v0, pb0, acc[ds], 0, 0, 0);
                acc[ds] = __builtin_amdgcn_mfma_f32_16x16x32_bf16(v1, pb1, acc[ds], 0, 0, 0);
            }
        }

        ls += __shfl_xor(ls, 16);
        ls += __shfl_xor(ls, 32);
        // bf16 partials (packed pairs)
        ushort_t* pa = pacc + ((size_t)pidx * 64 + w * 16 + l15) * 64 + l4 * 4;
#pragma unroll
        for (int ds = 0; ds < 4; ++ds) {
            uint2 pk;
            pk.x = cvt_pk_bf16(acc[ds][0], acc[ds][1]);
            pk.y = cvt_pk_bf16(acc[ds][2], acc[ds][3]);
            *(uint2*)(pa + ds * 16) = pk;
        }
        if (l4 == 0) {
            pm[pidx * 64 + w * 16 + l15] = mm;
            pl[pidx * 64 + w * 16 + l15] = ls;
        }
    };

    run_phase(jp,      (b * 64 + jp) * NPAR + v);
    run_phase(63 - jp, (b * 64 + 63 - jp) * NPAR + v);
}

// ---------------- Stage 2: combine the 6 parity partials per 64-row range -------------
__global__ __launch_bounds__(256) void combine_kernel(
    const ushort_t* __restrict__ pacc, const float* __restrict__ pm, const float* __restrict__ pl,
    float* __restrict__ out)
{
    const int g   = blockIdx.x;        // b*64 + r
    const int t   = threadIdx.x;
    const int row = t >> 2;            // 0..63
    const int d0  = (t & 3) * 16;
    float mv[NPAR], lv[NPAR];
#pragma unroll
    for (int p = 0; p < NPAR; ++p) {
        mv[p] = pm[(g * NPAR + p) * 64 + row];
        lv[p] = pl[(g * NPAR + p) * 64 + row];
    }
    float ms = mv[0];
#pragma unroll
    for (int p = 1; p < NPAR; ++p) ms = fmaxf(ms, mv[p]);
    float e[NPAR], ll = 0.f;
#pragma unroll
    for (int p = 0; p < NPAR; ++p) { e[p] = __expf(mv[p] - ms); ll += lv[p] * e[p]; }
    const float inv = 1.f / ll;
    float o[16];
#pragma unroll
    for (int i = 0; i < 16; ++i) o[i] = 0.f;
#pragma unroll
    for (int p = 0; p < NPAR; ++p) {
        const ushort_t* src = pacc + ((size_t)(g * NPAR + p) * 64 + row) * 64 + d0;
        short8 s0 = *(const short8*)(src);
        short8 s1 = *(const short8*)(src + 8);
#pragma unroll
        for (int i = 0; i < 8; ++i) {
            o[i]     += bf2f((ushort_t)s0[i]) * e[p];
            o[8 + i] += bf2f((ushort_t)s1[i]) * e[p];
        }
    }
    float4* op = (float4*)&out[((size_t)g * 64 + row) * 64 + d0];
#pragma unroll
    for (int i = 0; i < 4; ++i)
        op[i] = make_float4(o[i*4] * inv, o[i*4+1] * inv, o[i*4+2] * inv, o[i*4+3] * inv);
}

extern "C" void kernel_launch(void* const* d_in, const int* in_sizes, int n_in,
                              void* d_out, int out_size, void* d_ws, size_t ws_size,
                              hipStream_t stream) {
    const float* x  = (const float*)d_in[0];
    const float* Wq = (const float*)d_in[1];
    const float* Wk = (const float*)d_in[2];
    const float* Wv = (const float*)d_in[3];
    float* out = (float*)d_out;

    const int rows = in_sizes[0] / EMBD;   // B*S = 16384
    const int B    = rows / S_LEN;         // 4

    ushort_t* Qb = (ushort_t*)d_ws;
    ushort_t* Kb = Qb + (size_t)rows * HS;
    ushort_t* Vt = Kb + (size_t)rows * HS;
    ushort_t* Wt = Vt + (size_t)rows * HS;
    ushort_t* pacc = Wt + 192 * EMBD;                        // bf16 [B*64*6][64][64]
    float* pm = (float*)(pacc + (size_t)B * 64 * NPAR * 64 * 64);
    float* pl = pm + (size_t)B * 64 * NPAR * 64;

    hipLaunchKernelGGL(wprep_kernel, dim3(36), dim3(256), 0, stream, Wq, Wk, Wv, Wt);
    hipLaunchKernelGGL(qkv_kernel, dim3(rows / 32), dim3(512), 0, stream,
                       x, Wt, Qb, Kb, Vt);
    hipLaunchKernelGGL(attn_kernel, dim3(B * 32 * NPAR), dim3(256), 0, stream,
                       Qb, Kb, Vt, pacc, pm, pl);
    hipLaunchKernelGGL(combine_kernel, dim3(B * 64), dim3(256), 0, stream,
                       pacc, pm, pl, out);
}